// Round 4
// baseline (1992.095 us; speedup 1.0000x reference)
//
#include <hip/hip_runtime.h>
#include <cstdint>
#include <cstddef>

// MixedAttention: qkv GEMM -> {neighborhood attn | global self attn} -> proj GEMM
// Inputs fp32, output fp32 (out_npz 8.75MB == fp32 size; bf16 raw would be 4.7MB).
// Workspace fp32 (37.7MB; proven safe: rounds 2/3 bit-identical).

#define DIMC 512
#define HEADS 8
#define HD 32          // head dim = 512/8/2
#define KSZ 7
#define HH 48
#define WW 48
#define BB 2
#define NPIX (HH * WW)         // 2304
#define ROWS (BB * NPIX)       // 4608
#define C3 (3 * DIMC)          // 1536

// ---------------- GEMM: C[M,N] = A[M,K] @ B[K,N] + bias[N], fp32
// 64x64 tile, BK=16, 256 threads, 4x4 per thread.
template<int BM, int BN, int BK>
__global__ __launch_bounds__(256)
void gemm_bias(const float* __restrict__ A, const float* __restrict__ Bm,
               const float* __restrict__ bias, float* __restrict__ C,
               int M, int N, int K)
{
    __shared__ float As[BK][BM + 4];   // 68-float rows: conflict-broken
    __shared__ float Bs[BK][BN + 4];
    const int tid = threadIdx.x;
    const int tx = tid & 15, ty = tid >> 4;
    const int m0 = blockIdx.y * BM, n0 = blockIdx.x * BN;
    float acc[4][4] = {};
    for (int k0 = 0; k0 < K; k0 += BK) {
        {   // A tile 64x16, float4 per thread along K, store transposed
            const int m = tid >> 2, kq = (tid & 3) * 4;
            const float4 a4 = *reinterpret_cast<const float4*>(A + (size_t)(m0 + m) * K + k0 + kq);
            As[kq + 0][m] = a4.x;
            As[kq + 1][m] = a4.y;
            As[kq + 2][m] = a4.z;
            As[kq + 3][m] = a4.w;
        }
        {   // B tile 16x64, float4 per thread along N
            const int kb = tid >> 4, nq = (tid & 15) * 4;
            const float4 b4 = *reinterpret_cast<const float4*>(Bm + (size_t)(k0 + kb) * N + n0 + nq);
            Bs[kb][nq + 0] = b4.x;
            Bs[kb][nq + 1] = b4.y;
            Bs[kb][nq + 2] = b4.z;
            Bs[kb][nq + 3] = b4.w;
        }
        __syncthreads();
        #pragma unroll
        for (int kk = 0; kk < BK; ++kk) {
            const float4 av = *reinterpret_cast<const float4*>(&As[kk][ty * 4]);
            const float4 bv = *reinterpret_cast<const float4*>(&Bs[kk][tx * 4]);
            const float a_[4] = {av.x, av.y, av.z, av.w};
            const float b_[4] = {bv.x, bv.y, bv.z, bv.w};
            #pragma unroll
            for (int i = 0; i < 4; ++i)
                #pragma unroll
                for (int j = 0; j < 4; ++j)
                    acc[i][j] = fmaf(a_[i], b_[j], acc[i][j]);
        }
        __syncthreads();
    }
    float bv[4];
    #pragma unroll
    for (int j = 0; j < 4; ++j) bv[j] = bias[n0 + tx * 4 + j];
    #pragma unroll
    for (int i = 0; i < 4; ++i) {
        const size_t roff = (size_t)(m0 + ty * 4 + i) * N + n0 + tx * 4;
        float4 st;
        st.x = acc[i][0] + bv[0];
        st.y = acc[i][1] + bv[1];
        st.z = acc[i][2] + bv[2];
        st.w = acc[i][3] + bv[3];
        *reinterpret_cast<float4*>(C + roff) = st;
    }
}

// ---------------- Neighborhood attention: one wave per (b,h,pixel)
// lanes 0..48 = 7x7 window entries; wave softmax; 32-lane coalesced PV.
__global__ __launch_bounds__(256)
void na_attn(const float* __restrict__ qkv, const float* __restrict__ rpb,
             float* __restrict__ attn)
{
    const int wave = threadIdx.x >> 6, lane = threadIdx.x & 63;
    const int item = blockIdx.x * 4 + wave;           // (b*8+h)*2304 + pix
    const int pix = item % NPIX;
    const int bh = item / NPIX;
    const int h = bh & (HEADS - 1);
    const int b = bh >> 3;
    const int i = pix / WW, j = pix % WW;
    const int ni = min(max(i - 3, 0), HH - KSZ);
    const int nj = min(max(j - 3, 0), WW - KSZ);
    const int pi = 3 + max(3 - i, 0) + ((i + 3 >= HH) ? (HH - i - 4) : 0);
    const int pj = 3 + max(3 - j, 0) + ((j + 3 >= WW) ? (WW - j - 4) : 0);
    const float scale = 0.17677669529663687f;

    __shared__ float qsm[4][HD];
    __shared__ float aw[4][64];
    __shared__ int   rsm[4][64];

    const size_t rowbase = (size_t)b * NPIX;
    if (lane < HD)
        qsm[wave][lane] = qkv[(rowbase + pix) * C3 + h * HD + lane] * scale;
    __syncthreads();

    float sc = -1e30f;
    int nrow = 0;
    if (lane < KSZ * KSZ) {
        const int ki = lane / KSZ, kj = lane % KSZ;
        nrow = (ni + ki) * WW + (nj + kj);
        const float* kp = qkv + (rowbase + nrow) * C3 + 256 + h * HD;
        float acc = 0.f;
        #pragma unroll
        for (int d = 0; d < HD; d += 4) {
            const float4 kv = *reinterpret_cast<const float4*>(kp + d);
            acc = fmaf(qsm[wave][d + 0], kv.x, acc);
            acc = fmaf(qsm[wave][d + 1], kv.y, acc);
            acc = fmaf(qsm[wave][d + 2], kv.z, acc);
            acc = fmaf(qsm[wave][d + 3], kv.w, acc);
        }
        sc = acc + rpb[h * 169 + (pi + ki) * 13 + (pj + kj)];
    }
    float m = sc;
    #pragma unroll
    for (int off = 32; off > 0; off >>= 1) m = fmaxf(m, __shfl_xor(m, off));
    float e = (lane < KSZ * KSZ) ? __expf(sc - m) : 0.f;
    float s = e;
    #pragma unroll
    for (int off = 32; off > 0; off >>= 1) s += __shfl_xor(s, off);
    aw[wave][lane] = e / s;
    rsm[wave][lane] = nrow;
    __syncthreads();

    if (lane < HD) {
        float acc = 0.f;
        for (int l = 0; l < KSZ * KSZ; ++l) {
            const float a = aw[wave][l];
            const size_t r = rowbase + rsm[wave][l];
            acc = fmaf(a, qkv[r * C3 + 512 + h * HD + lane], acc);
        }
        attn[(rowbase + pix) * DIMC + h * HD + lane] = acc;
    }
}

// ---------------- Global self-attention: one block per (b,h,query row)
__global__ __launch_bounds__(256)
void self_attn(const float* __restrict__ qkv, float* __restrict__ attn)
{
    const int idx = blockIdx.x;
    const int qi = idx % NPIX;
    const int bh = idx / NPIX;
    const int h = bh & (HEADS - 1);
    const int b = bh >> 3;
    const float scale = 0.17677669529663687f;

    __shared__ float sc[NPIX];
    __shared__ float red[8];
    __shared__ float qs[HD];
    __shared__ float part[8][HD];

    const int t = threadIdx.x;
    const size_t rowbase = (size_t)b * NPIX;
    if (t < HD)
        qs[t] = qkv[(rowbase + qi) * C3 + 768 + h * HD + t] * scale;
    __syncthreads();

    for (int m = t; m < NPIX; m += 256) {
        const float* kp = qkv + (rowbase + m) * C3 + 1024 + h * HD;
        float acc = 0.f;
        #pragma unroll
        for (int d = 0; d < HD; d += 4) {
            const float4 kv = *reinterpret_cast<const float4*>(kp + d);
            acc = fmaf(qs[d + 0], kv.x, acc);
            acc = fmaf(qs[d + 1], kv.y, acc);
            acc = fmaf(qs[d + 2], kv.z, acc);
            acc = fmaf(qs[d + 3], kv.w, acc);
        }
        sc[m] = acc;
    }
    __syncthreads();

    const int lane = t & 63, wv = t >> 6;
    float lm = -1e30f;
    for (int m = t; m < NPIX; m += 256) lm = fmaxf(lm, sc[m]);
    #pragma unroll
    for (int off = 32; off > 0; off >>= 1) lm = fmaxf(lm, __shfl_xor(lm, off));
    if (lane == 0) red[wv] = lm;
    __syncthreads();
    const float gm = fmaxf(fmaxf(red[0], red[1]), fmaxf(red[2], red[3]));

    float ls = 0.f;
    for (int m = t; m < NPIX; m += 256) {
        const float e = __expf(sc[m] - gm);
        sc[m] = e;
        ls += e;
    }
    #pragma unroll
    for (int off = 32; off > 0; off >>= 1) ls += __shfl_xor(ls, off);
    if (lane == 0) red[4 + wv] = ls;
    __syncthreads();
    const float inv = 1.f / (red[4] + red[5] + red[6] + red[7]);

    const int d = t & 31, ch = t >> 5;       // 8 chunks x 288 keys
    float acc = 0.f;
    const float* vp = qkv + rowbase * C3 + 1280 + h * HD + d;
    for (int m = ch * 288; m < ch * 288 + 288; ++m)
        acc = fmaf(sc[m], vp[(size_t)m * C3], acc);
    part[ch][d] = acc;
    __syncthreads();

    if (t < HD) {
        float o = 0.f;
        #pragma unroll
        for (int c = 0; c < 8; ++c) o += part[c][t];
        attn[(rowbase + qi) * DIMC + 256 + h * HD + t] = o * inv;
    }
}

extern "C" void kernel_launch(void* const* d_in, const int* in_sizes, int n_in,
                              void* d_out, int out_size, void* d_ws, size_t ws_size,
                              hipStream_t stream)
{
    const float* x     = (const float*)d_in[0];
    const float* Wqkv  = (const float*)d_in[1];
    const float* bqkv  = (const float*)d_in[2];
    const float* rpb   = (const float*)d_in[3];
    const float* Wproj = (const float*)d_in[4];
    const float* bproj = (const float*)d_in[5];

    float* qkv  = (float*)d_ws;                          // ROWS x C3 fp32  (28.3 MB)
    float* attn = qkv + (size_t)ROWS * C3;               // ROWS x DIM fp32 ( 9.4 MB)

    const dim3 blk(256);
    // qkv = x @ W_qkv + b_qkv     (4608 x 1536 x 512)
    gemm_bias<64, 64, 16><<<dim3(C3 / 64, ROWS / 64), blk, 0, stream>>>(
        x, Wqkv, bqkv, qkv, ROWS, C3, DIMC);
    // NA attention -> attn[:, 0:256)
    na_attn<<<dim3((BB * HEADS * NPIX) / 4), blk, 0, stream>>>(qkv, rpb, attn);
    // self attention -> attn[:, 256:512)
    self_attn<<<dim3(BB * HEADS * NPIX), blk, 0, stream>>>(qkv, attn);
    // out = attn @ W_proj + b_proj (4608 x 512 x 512), fp32 out
    gemm_bias<64, 64, 16><<<dim3(DIMC / 64, ROWS / 64), blk, 0, stream>>>(
        attn, Wproj, bproj, (float*)d_out, ROWS, DIMC, DIMC);
}

// Round 5
// 732.593 us; speedup vs baseline: 2.7192x; 2.7192x over previous
//
#include <hip/hip_runtime.h>
#include <cstdint>
#include <cstddef>

// MixedAttention: qkv GEMM -> {neighborhood attn | flash self attn} -> proj GEMM
// Inputs fp32, output fp32. Self-attn: split-K flash, partials staged in d_out
// (dead until gemm2), combine kernel merges into attn buffer.

#define DIMC 512
#define HEADS 8
#define HD 32
#define KSZ 7
#define HH 48
#define WW 48
#define BB 2
#define NPIX (HH * WW)         // 2304
#define ROWS (BB * NPIX)       // 4608
#define C3 (3 * DIMC)          // 1536
#define TK 32                  // key tile
#define KSPLIT 4
#define KCHUNK (NPIX / KSPLIT) // 576
#define NTILES (KCHUNK / TK)   // 18
#define NQBLK (NPIX / 64)      // 36

static __device__ __forceinline__ float bf2f(uint32_t u) {
    return __builtin_bit_cast(float, u << 16);
}
static __device__ __forceinline__ uint16_t f2bf(float f) {
    uint32_t x = __builtin_bit_cast(uint32_t, f);
    uint32_t r = x + 0x7fffu + ((x >> 16) & 1u);
    return (uint16_t)(r >> 16);
}

// ---------------- GEMM: C[M,N] = A[M,K] @ B[K,N] + bias[N], fp32
template<int BM, int BN, int BK>
__global__ __launch_bounds__(256)
void gemm_bias(const float* __restrict__ A, const float* __restrict__ Bm,
               const float* __restrict__ bias, float* __restrict__ C,
               int M, int N, int K)
{
    __shared__ float As[BK][BM + 4];
    __shared__ float Bs[BK][BN + 4];
    const int tid = threadIdx.x;
    const int tx = tid & 15, ty = tid >> 4;
    const int m0 = blockIdx.y * BM, n0 = blockIdx.x * BN;
    float acc[4][4] = {};
    for (int k0 = 0; k0 < K; k0 += BK) {
        {
            const int m = tid >> 2, kq = (tid & 3) * 4;
            const float4 a4 = *reinterpret_cast<const float4*>(A + (size_t)(m0 + m) * K + k0 + kq);
            As[kq + 0][m] = a4.x;
            As[kq + 1][m] = a4.y;
            As[kq + 2][m] = a4.z;
            As[kq + 3][m] = a4.w;
        }
        {
            const int kb = tid >> 4, nq = (tid & 15) * 4;
            const float4 b4 = *reinterpret_cast<const float4*>(Bm + (size_t)(k0 + kb) * N + n0 + nq);
            Bs[kb][nq + 0] = b4.x;
            Bs[kb][nq + 1] = b4.y;
            Bs[kb][nq + 2] = b4.z;
            Bs[kb][nq + 3] = b4.w;
        }
        __syncthreads();
        #pragma unroll
        for (int kk = 0; kk < BK; ++kk) {
            const float4 av = *reinterpret_cast<const float4*>(&As[kk][ty * 4]);
            const float4 bv = *reinterpret_cast<const float4*>(&Bs[kk][tx * 4]);
            const float a_[4] = {av.x, av.y, av.z, av.w};
            const float b_[4] = {bv.x, bv.y, bv.z, bv.w};
            #pragma unroll
            for (int i = 0; i < 4; ++i)
                #pragma unroll
                for (int j = 0; j < 4; ++j)
                    acc[i][j] = fmaf(a_[i], b_[j], acc[i][j]);
        }
        __syncthreads();
    }
    float bv[4];
    #pragma unroll
    for (int j = 0; j < 4; ++j) bv[j] = bias[n0 + tx * 4 + j];
    #pragma unroll
    for (int i = 0; i < 4; ++i) {
        const size_t roff = (size_t)(m0 + ty * 4 + i) * N + n0 + tx * 4;
        float4 st;
        st.x = acc[i][0] + bv[0];
        st.y = acc[i][1] + bv[1];
        st.z = acc[i][2] + bv[2];
        st.w = acc[i][3] + bv[3];
        *reinterpret_cast<float4*>(C + roff) = st;
    }
}

// ---------------- Neighborhood attention (unchanged)
__global__ __launch_bounds__(256)
void na_attn(const float* __restrict__ qkv, const float* __restrict__ rpb,
             float* __restrict__ attn)
{
    const int wave = threadIdx.x >> 6, lane = threadIdx.x & 63;
    const int item = blockIdx.x * 4 + wave;
    const int pix = item % NPIX;
    const int bh = item / NPIX;
    const int h = bh & (HEADS - 1);
    const int b = bh >> 3;
    const int i = pix / WW, j = pix % WW;
    const int ni = min(max(i - 3, 0), HH - KSZ);
    const int nj = min(max(j - 3, 0), WW - KSZ);
    const int pi = 3 + max(3 - i, 0) + ((i + 3 >= HH) ? (HH - i - 4) : 0);
    const int pj = 3 + max(3 - j, 0) + ((j + 3 >= WW) ? (WW - j - 4) : 0);
    const float scale = 0.17677669529663687f;

    __shared__ float qsm[4][HD];
    __shared__ float aw[4][64];
    __shared__ int   rsm[4][64];

    const size_t rowbase = (size_t)b * NPIX;
    if (lane < HD)
        qsm[wave][lane] = qkv[(rowbase + pix) * C3 + h * HD + lane] * scale;
    __syncthreads();

    float sc = -1e30f;
    int nrow = 0;
    if (lane < KSZ * KSZ) {
        const int ki = lane / KSZ, kj = lane % KSZ;
        nrow = (ni + ki) * WW + (nj + kj);
        const float* kp = qkv + (rowbase + nrow) * C3 + 256 + h * HD;
        float acc = 0.f;
        #pragma unroll
        for (int d = 0; d < HD; d += 4) {
            const float4 kv = *reinterpret_cast<const float4*>(kp + d);
            acc = fmaf(qsm[wave][d + 0], kv.x, acc);
            acc = fmaf(qsm[wave][d + 1], kv.y, acc);
            acc = fmaf(qsm[wave][d + 2], kv.z, acc);
            acc = fmaf(qsm[wave][d + 3], kv.w, acc);
        }
        sc = acc + rpb[h * 169 + (pi + ki) * 13 + (pj + kj)];
    }
    float m = sc;
    #pragma unroll
    for (int off = 32; off > 0; off >>= 1) m = fmaxf(m, __shfl_xor(m, off));
    float e = (lane < KSZ * KSZ) ? __expf(sc - m) : 0.f;
    float s = e;
    #pragma unroll
    for (int off = 32; off > 0; off >>= 1) s += __shfl_xor(s, off);
    aw[wave][lane] = e / s;
    rsm[wave][lane] = nrow;
    __syncthreads();

    if (lane < HD) {
        float acc = 0.f;
        for (int l = 0; l < KSZ * KSZ; ++l) {
            const float a = aw[wave][l];
            const size_t r = rowbase + rsm[wave][l];
            acc = fmaf(a, qkv[r * C3 + 512 + h * HD + lane], acc);
        }
        attn[(rowbase + pix) * DIMC + h * HD + lane] = acc;
    }
}

// ---------------- Flash self-attention, split-K. One wave per block.
// Each lane owns one query (q,out,scores in regs); K/V tiles broadcast from LDS.
// Partials: normalized out (bf16) -> po (=d_out scratch), (m,l) fp32 -> pml (ws).
__global__ __launch_bounds__(64)
void self_attn_flash(const float* __restrict__ qkv,
                     uint16_t* __restrict__ po, float2* __restrict__ pml)
{
    const int lane = threadIdx.x;
    const int bid = blockIdx.x;               // [bh][qblk][split]
    const int split = bid & (KSPLIT - 1);
    const int qblk = (bid >> 2) % NQBLK;
    const int bh = bid / (KSPLIT * NQBLK);
    const int h = bh & (HEADS - 1);
    const int b = bh >> 3;
    const int q = qblk * 64 + lane;
    const size_t rowbase = (size_t)b * NPIX;
    const float scale = 0.17677669529663687f;

    __shared__ float4 Ks[TK][8];
    __shared__ float4 Vs[TK][8];

    float4 qf[8];
    {
        const float* qp = qkv + (rowbase + q) * C3 + 768 + h * HD;
        #pragma unroll
        for (int c = 0; c < 8; ++c) {
            float4 v = *reinterpret_cast<const float4*>(qp + c * 4);
            v.x *= scale; v.y *= scale; v.z *= scale; v.w *= scale;
            qf[c] = v;
        }
    }

    float m = -1e30f, l = 0.f;
    float4 of[8];
    #pragma unroll
    for (int c = 0; c < 8; ++c) of[c] = make_float4(0.f, 0.f, 0.f, 0.f);

    int k0 = split * KCHUNK;
    for (int t = 0; t < NTILES; ++t, k0 += TK) {
        __syncthreads();
        #pragma unroll
        for (int i = 0; i < 4; ++i) {
            const int fi = lane * 4 + i;       // 0..255
            const int r = fi >> 3, c = fi & 7;
            const float* kp = qkv + (rowbase + k0 + r) * C3 + 1024 + h * HD + c * 4;
            Ks[r][c] = *reinterpret_cast<const float4*>(kp);
            Vs[r][c] = *reinterpret_cast<const float4*>(kp + 256);  // V at 1280
        }
        __syncthreads();

        float s[TK];
        float tmax = -1e30f;
        #pragma unroll
        for (int j = 0; j < TK; ++j) {
            float acc = 0.f;
            #pragma unroll
            for (int c = 0; c < 8; ++c) {
                const float4 kv = Ks[j][c];
                acc = fmaf(qf[c].x, kv.x, acc);
                acc = fmaf(qf[c].y, kv.y, acc);
                acc = fmaf(qf[c].z, kv.z, acc);
                acc = fmaf(qf[c].w, kv.w, acc);
            }
            s[j] = acc;
            tmax = fmaxf(tmax, acc);
        }
        const float newm = fmaxf(m, tmax);
        const float corr = __expf(m - newm);   // first tile: exp(-1e30)=0
        l *= corr;
        #pragma unroll
        for (int c = 0; c < 8; ++c) {
            of[c].x *= corr; of[c].y *= corr; of[c].z *= corr; of[c].w *= corr;
        }
        m = newm;
        #pragma unroll
        for (int j = 0; j < TK; ++j) {
            const float p = __expf(s[j] - m);
            l += p;
            #pragma unroll
            for (int c = 0; c < 8; ++c) {
                const float4 vv = Vs[j][c];
                of[c].x = fmaf(p, vv.x, of[c].x);
                of[c].y = fmaf(p, vv.y, of[c].y);
                of[c].z = fmaf(p, vv.z, of[c].z);
                of[c].w = fmaf(p, vv.w, of[c].w);
            }
        }
    }

    // normalize per split, store bf16 partial + (m,l)
    const float invl = 1.f / l;
    const size_t item = ((size_t)split * 16 + bh) * NPIX + q;
    uint32_t packed[16];
    #pragma unroll
    for (int c = 0; c < 8; ++c) {
        packed[c * 2 + 0] = (uint32_t)f2bf(of[c].x * invl) | ((uint32_t)f2bf(of[c].y * invl) << 16);
        packed[c * 2 + 1] = (uint32_t)f2bf(of[c].z * invl) | ((uint32_t)f2bf(of[c].w * invl) << 16);
    }
    uint32_t* dst = reinterpret_cast<uint32_t*>(po + item * HD);
    #pragma unroll
    for (int w = 0; w < 4; ++w) {
        uint4 st;
        st.x = packed[w * 4 + 0]; st.y = packed[w * 4 + 1];
        st.z = packed[w * 4 + 2]; st.w = packed[w * 4 + 3];
        *reinterpret_cast<uint4*>(dst + w * 4) = st;
    }
    pml[item] = make_float2(m, l);
}

// ---------------- Combine split-K partials -> attn[:, 256:512)
__global__ __launch_bounds__(256)
void self_attn_combine(const uint16_t* __restrict__ po, const float2* __restrict__ pml,
                       float* __restrict__ attn)
{
    const int idx = blockIdx.x * 256 + threadIdx.x;   // 16*2304*32
    const int d = idx & (HD - 1);
    const int q = (idx >> 5) % NPIX;
    const int bh = idx / (HD * NPIX);
    const int h = bh & (HEADS - 1);
    const int b = bh >> 3;

    float2 ml[KSPLIT];
    float M = -1e30f;
    #pragma unroll
    for (int s = 0; s < KSPLIT; ++s) {
        ml[s] = pml[((size_t)s * 16 + bh) * NPIX + q];
        M = fmaxf(M, ml[s].x);
    }
    float num = 0.f, den = 0.f;
    #pragma unroll
    for (int s = 0; s < KSPLIT; ++s) {
        const float w = __expf(ml[s].x - M) * ml[s].y;
        const float o = bf2f((uint32_t)po[(((size_t)s * 16 + bh) * NPIX + q) * HD + d]);
        num = fmaf(w, o, num);
        den += w;
    }
    attn[((size_t)b * NPIX + q) * DIMC + 256 + h * HD + d] = num / den;
}

extern "C" void kernel_launch(void* const* d_in, const int* in_sizes, int n_in,
                              void* d_out, int out_size, void* d_ws, size_t ws_size,
                              hipStream_t stream)
{
    const float* x     = (const float*)d_in[0];
    const float* Wqkv  = (const float*)d_in[1];
    const float* bqkv  = (const float*)d_in[2];
    const float* rpb   = (const float*)d_in[3];
    const float* Wproj = (const float*)d_in[4];
    const float* bproj = (const float*)d_in[5];

    float* qkv  = (float*)d_ws;                           // ROWS x C3 fp32   (28.3 MB)
    float* attn = qkv + (size_t)ROWS * C3;                // ROWS x DIMC fp32 ( 9.4 MB)
    float2* pml = (float2*)(attn + (size_t)ROWS * DIMC);  // KSPLIT*16*NPIX   ( 1.2 MB)
    uint16_t* po = (uint16_t*)d_out;                      // partial bf16 scratch, dead after combine

    const dim3 blk(256);
    gemm_bias<64, 64, 16><<<dim3(C3 / 64, ROWS / 64), blk, 0, stream>>>(
        x, Wqkv, bqkv, qkv, ROWS, C3, DIMC);
    na_attn<<<dim3((BB * HEADS * NPIX) / 4), blk, 0, stream>>>(qkv, rpb, attn);
    self_attn_flash<<<dim3(16 * NQBLK * KSPLIT), dim3(64), 0, stream>>>(qkv, po, pml);
    self_attn_combine<<<dim3((16 * NPIX * HD) / 256), blk, 0, stream>>>(po, pml, attn);
    gemm_bias<64, 64, 16><<<dim3(DIMC / 64, ROWS / 64), blk, 0, stream>>>(
        attn, Wproj, bproj, (float*)d_out, ROWS, DIMC, DIMC);
}